// Round 1
// baseline (3767.429 us; speedup 1.0000x reference)
//
#include <hip/hip_runtime.h>
#include <math.h>

// Problem constants (from reference)
constexpr int NN = 50000;     // nodes
constexpr int NE = 800000;    // edges
constexpr int H  = 128;       // hidden
constexpr int ED = 16;        // edge dim
constexpr int NL = 3;         // layers
constexpr int NG = 256;       // graphs

// ---------------------------------------------------------------------------
// zero-fill (float4 granularity)
__global__ __launch_bounds__(256) void k_zero4(float4* __restrict__ a, int n4) {
    int i = blockIdx.x * 256 + threadIdx.x;
    if (i < n4) a[i] = make_float4(0.f, 0.f, 0.f, 0.f);
}

// ---------------------------------------------------------------------------
// transpose GRU weights: wT[m][l][k][r] = w_m[l][r][k]   (m: 0=wih, 1=whh)
__global__ __launch_bounds__(256) void k_transpose(const float* __restrict__ wih,
                                                   const float* __restrict__ whh,
                                                   float* __restrict__ wT) {
    int i = blockIdx.x * 256 + threadIdx.x;   // 2*3*128*384 = 294912
    if (i >= 2 * NL * 128 * 384) return;
    int m   = i / (NL * 49152);
    int rem = i % (NL * 49152);
    int l   = rem / 49152;
    int kr  = rem % 49152;          // k*384 + r  (write-coalesced)
    int k = kr / 384, r = kr % 384;
    const float* src = (m == 0 ? wih : whh) + (size_t)l * 49152;
    wT[i] = src[r * 128 + k];
}

// ---------------------------------------------------------------------------
// C[M,128] = act(A[M,128] @ W[128,128] (+bias))
template <bool RELU, bool BIAS>
__global__ __launch_bounds__(256) void k_gemm128(const float* __restrict__ A,
                                                 const float* __restrict__ W,
                                                 const float* __restrict__ bias,
                                                 float* __restrict__ C, int M) {
    __shared__ float As[32][132];
    const int t = threadIdx.x;
    const int row0 = blockIdx.x * 32;

    {
        const float4* A4 = (const float4*)(A + (size_t)row0 * H);
        #pragma unroll
        for (int i = 0; i < 4; ++i) {
            int idx = t + i * 256;            // 0..1023  (= r*32 + c4)
            int r = idx >> 5, c4 = idx & 31;
            float4 v = make_float4(0.f, 0.f, 0.f, 0.f);
            if (row0 + r < M) v = A4[idx];
            *(float4*)&As[r][c4 * 4] = v;
        }
    }
    __syncthreads();

    const int cg = t & 31;    // cols cg*4 .. cg*4+3
    const int rg = t >> 5;    // rows rg*4 .. rg*4+3
    float acc[4][4];
    #pragma unroll
    for (int i = 0; i < 4; ++i)
        #pragma unroll
        for (int j = 0; j < 4; ++j) acc[i][j] = 0.f;

    #pragma unroll 4
    for (int k = 0; k < H; k += 4) {
        float4 w0 = *(const float4*)(W + (size_t)(k + 0) * H + cg * 4);
        float4 w1 = *(const float4*)(W + (size_t)(k + 1) * H + cg * 4);
        float4 w2 = *(const float4*)(W + (size_t)(k + 2) * H + cg * 4);
        float4 w3 = *(const float4*)(W + (size_t)(k + 3) * H + cg * 4);
        #pragma unroll
        for (int i = 0; i < 4; ++i) {
            float4 av = *(const float4*)&As[rg * 4 + i][k];
            acc[i][0] += av.x * w0.x + av.y * w1.x + av.z * w2.x + av.w * w3.x;
            acc[i][1] += av.x * w0.y + av.y * w1.y + av.z * w2.y + av.w * w3.y;
            acc[i][2] += av.x * w0.z + av.y * w1.z + av.z * w2.z + av.w * w3.z;
            acc[i][3] += av.x * w0.w + av.y * w1.w + av.z * w2.w + av.w * w3.w;
        }
    }

    float4 bv = make_float4(0.f, 0.f, 0.f, 0.f);
    if (BIAS) bv = *(const float4*)(bias + cg * 4);
    #pragma unroll
    for (int i = 0; i < 4; ++i) {
        int row = row0 + rg * 4 + i;
        if (row < M) {
            float4 o;
            o.x = acc[i][0] + bv.x; o.y = acc[i][1] + bv.y;
            o.z = acc[i][2] + bv.z; o.w = acc[i][3] + bv.w;
            if (RELU) {
                o.x = fmaxf(o.x, 0.f); o.y = fmaxf(o.y, 0.f);
                o.z = fmaxf(o.z, 0.f); o.w = fmaxf(o.w, 0.f);
            }
            *(float4*)(C + (size_t)row * H + cg * 4) = o;
        }
    }
}

// ---------------------------------------------------------------------------
// Edge MLP + scatter: for each edge e:
//   hid = relu(p[src] + ea@W1e + b1);  m = hid@W2 + b2;  agg[dst] += m
// blockIdx.y selects output-column half (64 cols) so LDS stays < 64 KB.
// Persistent grid-stride over 16-edge chunks (NE % 16 == 0).
__global__ __launch_bounds__(256) void k_edge(const float* __restrict__ p,
                                              const float* __restrict__ ea,
                                              const int* __restrict__ ei,
                                              const float* __restrict__ w1e,  // [16][128]
                                              const float* __restrict__ b1,   // [128]
                                              const float* __restrict__ w2,   // [128][128]
                                              const float* __restrict__ b2,   // [128]
                                              float* __restrict__ agg) {
    __shared__ float W1e_s[16][128];   // 8 KB
    __shared__ float W2t_s[64][132];   // 33.8 KB (transposed half of W2)
    __shared__ float hid_s[16][132];   // 8.4 KB
    __shared__ float ea_s[16][16];
    __shared__ float b1_s[128];
    __shared__ float b2h_s[64];
    __shared__ int   src_s[16];
    __shared__ int   dst_s[16];

    const int t  = threadIdx.x;
    const int c0 = blockIdx.y * 64;

    for (int i = t; i < 16 * 128; i += 256) W1e_s[i >> 7][i & 127] = w1e[i];
    for (int i = t; i < 128 * 64; i += 256) {
        int k = i >> 6, j = i & 63;
        W2t_s[j][k] = w2[k * 128 + c0 + j];
    }
    if (t < 128) b1_s[t] = b1[t];
    else if (t < 192) b2h_s[t - 128] = b2[c0 + (t - 128)];
    __syncthreads();

    const int e1 = t >> 4;   // phase-1 edge 0..15
    const int kg = t & 15;   // phase-1 k-group
    const int wv = t >> 6;   // wave 0..3
    const int j  = t & 63;   // phase-2 column lane

    for (int base = blockIdx.x * 16; base < NE; base += gridDim.x * 16) {
        if (t < 16)       src_s[t] = ei[base + t];
        else if (t < 32)  dst_s[t - 16] = ei[NE + base + (t - 16)];
        {
            int e = t >> 4, q = t & 15;
            ea_s[e][q] = ea[(size_t)(base + e) * ED + q];
        }
        __syncthreads();

        // phase 1: hidden = relu(p[src] + ea@W1e + b1)
        {
            const float* prow = p + (size_t)src_s[e1] * H;
            float eav[16];
            #pragma unroll
            for (int q = 0; q < 16; ++q) eav[q] = ea_s[e1][q];
            #pragma unroll
            for (int i = 0; i < 8; ++i) {
                int k = kg + 16 * i;
                float v = prow[k] + b1_s[k];
                #pragma unroll
                for (int q = 0; q < 16; ++q) v += eav[q] * W1e_s[q][k];
                hid_s[e1][k] = fmaxf(v, 0.f);
            }
        }
        __syncthreads();

        // phase 2: m[c0+j] = hid @ W2half, 4 edges per wave share weight reads
        {
            const int e0 = wv * 4;
            float b2v = b2h_s[j];
            float a0 = b2v, a1 = b2v, a2 = b2v, a3 = b2v;
            #pragma unroll 4
            for (int k = 0; k < 128; k += 4) {
                float4 w  = *(const float4*)&W2t_s[j][k];
                float4 h0 = *(const float4*)&hid_s[e0 + 0][k];
                float4 h1 = *(const float4*)&hid_s[e0 + 1][k];
                float4 h2 = *(const float4*)&hid_s[e0 + 2][k];
                float4 h3 = *(const float4*)&hid_s[e0 + 3][k];
                a0 += h0.x * w.x + h0.y * w.y + h0.z * w.z + h0.w * w.w;
                a1 += h1.x * w.x + h1.y * w.y + h1.z * w.z + h1.w * w.w;
                a2 += h2.x * w.x + h2.y * w.y + h2.z * w.z + h2.w * w.w;
                a3 += h3.x * w.x + h3.y * w.y + h3.z * w.z + h3.w * w.w;
            }
            float* ag = agg + c0 + j;
            atomicAdd(ag + (size_t)dst_s[e0 + 0] * H, a0);
            atomicAdd(ag + (size_t)dst_s[e0 + 1] * H, a1);
            atomicAdd(ag + (size_t)dst_s[e0 + 2] * H, a2);
            atomicAdd(ag + (size_t)dst_s[e0 + 3] * H, a3);
        }
        __syncthreads();
    }
}

// ---------------------------------------------------------------------------
__device__ __forceinline__ float sigmoidf_(float x) { return 1.f / (1.f + expf(-x)); }

// fused GRUCell + BatchNorm(eval) + residual, 8 nodes per block
__global__ __launch_bounds__(256) void k_gru(const float* __restrict__ agg,
                                             float* __restrict__ h,
                                             const float* __restrict__ wihT,  // [128][384]
                                             const float* __restrict__ whhT,  // [128][384]
                                             const float* __restrict__ bih,
                                             const float* __restrict__ bhh,
                                             const float* __restrict__ gamma,
                                             const float* __restrict__ beta,
                                             const float* __restrict__ mean,
                                             const float* __restrict__ var) {
    __shared__ float aggs[8][128];
    __shared__ float hs[8][128];
    const int t = threadIdx.x;
    const int n0 = blockIdx.x * 8;   // NN % 8 == 0

    ((float4*)&aggs[0][0])[t] = ((const float4*)(agg + (size_t)n0 * H))[t];
    ((float4*)&hs[0][0])[t]   = ((const float4*)(h   + (size_t)n0 * H))[t];
    __syncthreads();

    const int c = t & 127;
    const int g = t >> 7;   // node group: nodes g*4 .. g*4+3

    const float bi_r = bih[c], bi_z = bih[128 + c], bi_n = bih[256 + c];
    const float bh_r = bhh[c], bh_z = bhh[128 + c], bh_n = bhh[256 + c];
    float ir[4], iz[4], inn[4], hr[4], hz[4], hn[4];
    #pragma unroll
    for (int n = 0; n < 4; ++n) {
        ir[n] = bi_r; iz[n] = bi_z; inn[n] = bi_n;
        hr[n] = bh_r; hz[n] = bh_z; hn[n]  = bh_n;
    }

    #pragma unroll 2
    for (int k = 0; k < 128; ++k) {
        float wir = wihT[k * 384 + c];
        float wiz = wihT[k * 384 + 128 + c];
        float win = wihT[k * 384 + 256 + c];
        float whr = whhT[k * 384 + c];
        float whz = whhT[k * 384 + 128 + c];
        float whn = whhT[k * 384 + 256 + c];
        #pragma unroll
        for (int n = 0; n < 4; ++n) {
            float a  = aggs[g * 4 + n][k];
            float hv = hs[g * 4 + n][k];
            ir[n]  += a * wir;  iz[n] += a * wiz;  inn[n] += a * win;
            hr[n]  += hv * whr; hz[n] += hv * whz; hn[n]  += hv * whn;
        }
    }

    const float ga = gamma[c], be = beta[c], mu = mean[c];
    const float iv = rsqrtf(var[c] + 1e-5f);
    #pragma unroll
    for (int n = 0; n < 4; ++n) {
        int node = n0 + g * 4 + n;
        float r  = sigmoidf_(ir[n] + hr[n]);
        float z  = sigmoidf_(iz[n] + hz[n]);
        float nn = tanhf(inn[n] + r * hn[n]);
        float hv = hs[g * 4 + n][c];
        float hnew = (1.f - z) * nn + z * hv;
        float bn = (hnew - mu) * iv * ga + be;
        h[(size_t)node * H + c] = hv + bn;
    }
}

// ---------------------------------------------------------------------------
// readout
__device__ __forceinline__ unsigned fkey(float f) {
    unsigned b = __float_as_uint(f);
    return (b & 0x80000000u) ? ~b : (b | 0x80000000u);
}
__device__ __forceinline__ float funkey(unsigned k) {
    unsigned b = (k & 0x80000000u) ? (k & 0x7FFFFFFFu) : ~k;
    return __uint_as_float(b);
}

__global__ __launch_bounds__(256) void k_ro_init(float* __restrict__ gsum,
                                                 unsigned* __restrict__ gmaxb,
                                                 float* __restrict__ gcnt) {
    int i = blockIdx.x * 256 + threadIdx.x;
    if (i < NG * H) { gsum[i] = 0.f; gmaxb[i] = 0u; }
    if (i < NG) gcnt[i] = 0.f;
}

__global__ __launch_bounds__(256) void k_scatter(const float* __restrict__ h,
                                                 const int* __restrict__ batch,
                                                 float* __restrict__ gsum,
                                                 unsigned* __restrict__ gmaxb,
                                                 float* __restrict__ gcnt) {
    int idx = blockIdx.x * 256 + threadIdx.x;   // NN*H
    if (idx >= NN * H) return;
    int n = idx >> 7, c = idx & 127;
    int g = batch[n];
    float v = h[idx];
    atomicAdd(&gsum[g * H + c], v);
    atomicMax(&gmaxb[g * H + c], fkey(v));
    if (c == 0) atomicAdd(&gcnt[g], 1.f);
}

__global__ __launch_bounds__(128) void k_ro_final(const float* __restrict__ gsum,
                                                  const unsigned* __restrict__ gmaxb,
                                                  const float* __restrict__ gcnt,
                                                  const float* __restrict__ row,
                                                  const float* __restrict__ rob,
                                                  float* __restrict__ out) {
    __shared__ float cat[256];
    const int g = blockIdx.x, t = threadIdx.x;
    float cnt = gcnt[g];
    float inv = 1.f / fmaxf(cnt, 1.f);
    cat[t] = gsum[g * H + t] * inv;
    float mx = funkey(gmaxb[g * H + t]);
    cat[128 + t] = (cnt > 0.f) ? mx : 0.f;
    __syncthreads();
    float acc = rob[t];
    #pragma unroll 4
    for (int k = 0; k < 256; ++k) acc += cat[k] * row[k * H + t];
    out[g * H + t] = fmaxf(acc, 0.f);
}

// ---------------------------------------------------------------------------
extern "C" void kernel_launch(void* const* d_in, const int* in_sizes, int n_in,
                              void* d_out, int out_size, void* d_ws, size_t ws_size,
                              hipStream_t stream) {
    const float* x        = (const float*)d_in[0];
    const int*   ei       = (const int*)d_in[1];
    const float* ea       = (const float*)d_in[2];
    const int*   batch    = (const int*)d_in[3];
    const float* lin_in_w = (const float*)d_in[5];
    const float* lin_in_b = (const float*)d_in[6];
    const float* msg_w1   = (const float*)d_in[7];
    const float* msg_b1   = (const float*)d_in[8];
    const float* msg_w2   = (const float*)d_in[9];
    const float* msg_b2   = (const float*)d_in[10];
    const float* bn_gamma = (const float*)d_in[11];
    const float* bn_beta  = (const float*)d_in[12];
    const float* bn_mean  = (const float*)d_in[13];
    const float* bn_var   = (const float*)d_in[14];
    const float* gru_wih  = (const float*)d_in[15];
    const float* gru_whh  = (const float*)d_in[16];
    const float* gru_bih  = (const float*)d_in[17];
    const float* gru_bhh  = (const float*)d_in[18];
    const float* ro_w     = (const float*)d_in[19];
    const float* ro_b     = (const float*)d_in[20];

    float* ws = (float*)d_ws;
    float*    h     = ws;                       // 6,400,000
    float*    p     = ws + 6400000;             // 6,400,000
    float*    agg   = ws + 12800000;            // 6,400,000
    float*    gsum  = ws + 19200000;            // 32,768
    unsigned* gmaxb = (unsigned*)(ws + 19232768); // 32,768
    float*    gcnt  = ws + 19265536;            // 256
    float*    wT    = ws + 19265792;            // 294,912  (total ~78.2 MB)

    // transpose GRU weights once per launch
    k_transpose<<<1152, 256, 0, stream>>>(gru_wih, gru_whh, wT);

    // input projection: h = relu(x @ Win + b)
    k_gemm128<true, true><<<1563, 256, 0, stream>>>(x, lin_in_w, lin_in_b, h, NN);

    for (int l = 0; l < NL; ++l) {
        const float* w1  = msg_w1 + (size_t)l * 144 * 128;
        // p = h @ W1[:128,:]
        k_gemm128<false, false><<<1563, 256, 0, stream>>>(h, w1, nullptr, p, NN);
        // agg = 0
        k_zero4<<<6250, 256, 0, stream>>>((float4*)agg, 1600000);
        // edge MLP + scatter-add
        k_edge<<<dim3(768, 2), 256, 0, stream>>>(p, ea, ei,
                                                 w1 + 128 * 128, msg_b1 + l * 128,
                                                 msg_w2 + (size_t)l * 128 * 128,
                                                 msg_b2 + l * 128, agg);
        // GRU + BN + residual
        k_gru<<<6250, 256, 0, stream>>>(agg, h,
                                        wT + (size_t)l * 49152,
                                        wT + (size_t)(NL + l) * 49152,
                                        gru_bih + l * 384, gru_bhh + l * 384,
                                        bn_gamma + l * 128, bn_beta + l * 128,
                                        bn_mean + l * 128, bn_var + l * 128);
    }

    // readout
    k_ro_init<<<128, 256, 0, stream>>>(gsum, gmaxb, gcnt);
    k_scatter<<<25000, 256, 0, stream>>>(h, batch, gsum, gmaxb, gcnt);
    k_ro_final<<<NG, 128, 0, stream>>>(gsum, gmaxb, gcnt, ro_w, ro_b, (float*)d_out);
}

// Round 2
// 2119.870 us; speedup vs baseline: 1.7772x; 1.7772x over previous
//
#include <hip/hip_runtime.h>
#include <math.h>

// Problem constants (from reference)
constexpr int NN = 50000;     // nodes
constexpr int NE = 800000;    // edges
constexpr int H  = 128;       // hidden
constexpr int ED = 16;        // edge dim
constexpr int NL = 3;         // layers
constexpr int NG = 256;       // graphs

typedef __attribute__((ext_vector_type(8))) short bf8;    // 8 bf16 in 4 VGPRs
typedef __attribute__((ext_vector_type(4))) float f32x4;  // MFMA accumulator

__device__ __forceinline__ unsigned short f2bf(float f) {
    unsigned u = __float_as_uint(f);
    unsigned r = (u + 0x7FFFu + ((u >> 16) & 1u)) >> 16;   // RNE
    return (unsigned short)r;
}
__device__ __forceinline__ float bf2f(unsigned short b) {
    return __uint_as_float(((unsigned)b) << 16);
}

// ---------------------------------------------------------------------------
// zero-fill (float4 granularity)
__global__ __launch_bounds__(256) void k_zero4(float4* __restrict__ a, int n4) {
    int i = blockIdx.x * 256 + threadIdx.x;
    if (i < n4) a[i] = make_float4(0.f, 0.f, 0.f, 0.f);
}

// ---------------------------------------------------------------------------
// transpose GRU weights: wT[m][l][k][r] = w_m[l][r][k]   (m: 0=wih, 1=whh)
__global__ __launch_bounds__(256) void k_transpose(const float* __restrict__ wih,
                                                   const float* __restrict__ whh,
                                                   float* __restrict__ wT) {
    int i = blockIdx.x * 256 + threadIdx.x;   // 2*3*128*384 = 294912
    if (i >= 2 * NL * 128 * 384) return;
    int m   = i / (NL * 49152);
    int rem = i % (NL * 49152);
    int l   = rem / 49152;
    int kr  = rem % 49152;          // k*384 + r  (write-coalesced)
    int k = kr / 384, r = kr % 384;
    const float* src = (m == 0 ? wih : whh) + (size_t)l * 49152;
    wT[i] = src[r * 128 + k];
}

// ---------------------------------------------------------------------------
// prepare bf16 edge-MLP weights:
//   w1et[l][n][k] (128 x 32) = msg_w1[l][128+k][n]  (k<16), else 0
//   w2t [l][n][k] (128 x 128) = msg_w2[l][k][n]
__global__ __launch_bounds__(256) void k_prep(const float* __restrict__ w1,
                                              const float* __restrict__ w2,
                                              unsigned short* __restrict__ w1et,
                                              unsigned short* __restrict__ w2t) {
    int i = blockIdx.x * 256 + threadIdx.x;
    if (i < NL * 128 * 32) {
        int l = i / 4096, rem = i % 4096;
        int n = rem >> 5, k = rem & 31;
        float v = (k < ED) ? w1[(size_t)l * 144 * 128 + (size_t)(128 + k) * 128 + n] : 0.f;
        w1et[i] = f2bf(v);
        return;
    }
    int j = i - NL * 128 * 32;
    if (j < NL * 128 * 128) {
        int l = j / 16384, rem = j % 16384;
        int n = rem >> 7, k = rem & 127;
        w2t[j] = f2bf(w2[(size_t)l * 16384 + (size_t)k * 128 + n]);
    }
}

// ---------------------------------------------------------------------------
// C[M,128] = act(A[M,128] @ W[128,128] (+bias)); optional bf16 output
template <bool RELU, bool BIAS, bool OUTBF>
__global__ __launch_bounds__(256) void k_gemm128(const float* __restrict__ A,
                                                 const float* __restrict__ W,
                                                 const float* __restrict__ bias,
                                                 float* __restrict__ C,
                                                 unsigned short* __restrict__ Cb,
                                                 int M) {
    __shared__ float As[32][132];
    const int t = threadIdx.x;
    const int row0 = blockIdx.x * 32;

    {
        const float4* A4 = (const float4*)(A + (size_t)row0 * H);
        #pragma unroll
        for (int i = 0; i < 4; ++i) {
            int idx = t + i * 256;            // 0..1023  (= r*32 + c4)
            int r = idx >> 5, c4 = idx & 31;
            float4 v = make_float4(0.f, 0.f, 0.f, 0.f);
            if (row0 + r < M) v = A4[idx];
            *(float4*)&As[r][c4 * 4] = v;
        }
    }
    __syncthreads();

    const int cg = t & 31;    // cols cg*4 .. cg*4+3
    const int rg = t >> 5;    // rows rg*4 .. rg*4+3
    float acc[4][4];
    #pragma unroll
    for (int i = 0; i < 4; ++i)
        #pragma unroll
        for (int j = 0; j < 4; ++j) acc[i][j] = 0.f;

    #pragma unroll 4
    for (int k = 0; k < H; k += 4) {
        float4 w0 = *(const float4*)(W + (size_t)(k + 0) * H + cg * 4);
        float4 w1 = *(const float4*)(W + (size_t)(k + 1) * H + cg * 4);
        float4 w2 = *(const float4*)(W + (size_t)(k + 2) * H + cg * 4);
        float4 w3 = *(const float4*)(W + (size_t)(k + 3) * H + cg * 4);
        #pragma unroll
        for (int i = 0; i < 4; ++i) {
            float4 av = *(const float4*)&As[rg * 4 + i][k];
            acc[i][0] += av.x * w0.x + av.y * w1.x + av.z * w2.x + av.w * w3.x;
            acc[i][1] += av.x * w0.y + av.y * w1.y + av.z * w2.y + av.w * w3.y;
            acc[i][2] += av.x * w0.z + av.y * w1.z + av.z * w2.z + av.w * w3.z;
            acc[i][3] += av.x * w0.w + av.y * w1.w + av.z * w2.w + av.w * w3.w;
        }
    }

    float4 bv = make_float4(0.f, 0.f, 0.f, 0.f);
    if (BIAS) bv = *(const float4*)(bias + cg * 4);
    #pragma unroll
    for (int i = 0; i < 4; ++i) {
        int row = row0 + rg * 4 + i;
        if (row < M) {
            float o[4];
            o[0] = acc[i][0] + bv.x; o[1] = acc[i][1] + bv.y;
            o[2] = acc[i][2] + bv.z; o[3] = acc[i][3] + bv.w;
            if (RELU) {
                #pragma unroll
                for (int c = 0; c < 4; ++c) o[c] = fmaxf(o[c], 0.f);
            }
            if (OUTBF) {
                union { uint2 u; unsigned short s[4]; } pk;
                #pragma unroll
                for (int c = 0; c < 4; ++c) pk.s[c] = f2bf(o[c]);
                *(uint2*)(Cb + (size_t)row * H + cg * 4) = pk.u;
            } else {
                float4 ov = make_float4(o[0], o[1], o[2], o[3]);
                *(float4*)(C + (size_t)row * H + cg * 4) = ov;
            }
        }
    }
}

// ---------------------------------------------------------------------------
// MFMA edge kernel. Per 64-edge iteration:
//   hid = relu(p_bf[src] + ea@W1e + b1)   (phase 1, MFMA, C-layout)
//   m   = hid@W2 + b2 ; agg[dst] += m     (phase 2, MFMA, atomics)
// Each wave owns 32 output columns; W1e/W2 B-fragments live in registers
// for the whole (persistent) kernel. hid re-orients via LDS (stride 136 bf16).
__global__ __launch_bounds__(256, 3) void k_edge_mfma(
        const unsigned short* __restrict__ p,     // [NN][128] bf16
        const float* __restrict__ ea,             // [NE][16]
        const int* __restrict__ ei,               // [2][NE]
        const unsigned short* __restrict__ w1et,  // [128][32] bf16
        const float* __restrict__ b1,
        const unsigned short* __restrict__ w2t,   // [128][128] bf16
        const float* __restrict__ b2,
        float* __restrict__ agg) {
    __shared__ unsigned short hid_s[64][136];   // 17.4 KB, stride 272 B
    __shared__ int src_s[64], dst_s[64];

    const int t    = threadIdx.x;
    const int w    = t >> 6;     // wave 0..3 -> cols [w*32, w*32+32)
    const int lane = t & 63;
    const int l15  = lane & 15;
    const int q    = lane >> 4;

    // Load per-wave weight fragments once (persistent block).
    bf8 w1f[2];
    bf8 w2f[2][4];
    float b1v[2], b2v[2];
    #pragma unroll
    for (int nt = 0; nt < 2; ++nt) {
        int n = w * 32 + nt * 16 + l15;
        w1f[nt] = *(const bf8*)(w1et + (size_t)n * 32 + q * 8);
        #pragma unroll
        for (int ks = 0; ks < 4; ++ks)
            w2f[nt][ks] = *(const bf8*)(w2t + (size_t)n * 128 + ks * 32 + q * 8);
        b1v[nt] = b1[n];
        b2v[nt] = b2[n];
    }

    const f32x4 zero = {0.f, 0.f, 0.f, 0.f};

    for (int base = blockIdx.x * 64; base < NE; base += gridDim.x * 64) {
        if (t < 64)       src_s[t] = ei[base + t];
        else if (t < 128) dst_s[t - 64] = ei[NE + base + (t - 64)];
        __syncthreads();

        // ---- phase 1: hid = relu(p[src] + ea@W1e + b1)
        f32x4 acc1[4][2];
        #pragma unroll
        for (int mt = 0; mt < 4; ++mt) {
            bf8 af = {0, 0, 0, 0, 0, 0, 0, 0};
            if (q < 2) {
                const float4* e4 = (const float4*)(ea + (size_t)(base + mt * 16 + l15) * ED + q * 8);
                float4 v0 = e4[0], v1 = e4[1];
                af[0] = (short)f2bf(v0.x); af[1] = (short)f2bf(v0.y);
                af[2] = (short)f2bf(v0.z); af[3] = (short)f2bf(v0.w);
                af[4] = (short)f2bf(v1.x); af[5] = (short)f2bf(v1.y);
                af[6] = (short)f2bf(v1.z); af[7] = (short)f2bf(v1.w);
            }
            #pragma unroll
            for (int nt = 0; nt < 2; ++nt)
                acc1[mt][nt] = __builtin_amdgcn_mfma_f32_16x16x32_bf16(af, w1f[nt], zero, 0, 0, 0);
        }
        // add gathered p + b1, relu, write bf16 hid to LDS
        #pragma unroll
        for (int mt = 0; mt < 4; ++mt) {
            #pragma unroll
            for (int r = 0; r < 4; ++r) {
                int er = mt * 16 + q * 4 + r;       // edge row within the 64
                const unsigned short* prow = p + (size_t)src_s[er] * H;
                #pragma unroll
                for (int nt = 0; nt < 2; ++nt) {
                    int col = w * 32 + nt * 16 + l15;
                    float v = acc1[mt][nt][r] + bf2f(prow[col]) + b1v[nt];
                    hid_s[er][col] = f2bf(fmaxf(v, 0.f));
                }
            }
        }
        __syncthreads();

        // ---- phase 2: m = hid@W2 (+b2), scatter-add
        f32x4 acc2[4][2];
        #pragma unroll
        for (int mt = 0; mt < 4; ++mt)
            #pragma unroll
            for (int nt = 0; nt < 2; ++nt) acc2[mt][nt] = zero;

        #pragma unroll
        for (int ks = 0; ks < 4; ++ks) {
            #pragma unroll
            for (int mt = 0; mt < 4; ++mt) {
                bf8 af = *(const bf8*)&hid_s[mt * 16 + l15][ks * 32 + q * 8];
                acc2[mt][0] = __builtin_amdgcn_mfma_f32_16x16x32_bf16(af, w2f[0][ks], acc2[mt][0], 0, 0, 0);
                acc2[mt][1] = __builtin_amdgcn_mfma_f32_16x16x32_bf16(af, w2f[1][ks], acc2[mt][1], 0, 0, 0);
            }
        }

        #pragma unroll
        for (int mt = 0; mt < 4; ++mt) {
            #pragma unroll
            for (int r = 0; r < 4; ++r) {
                int er = mt * 16 + q * 4 + r;
                float* ag = agg + (size_t)dst_s[er] * H;
                #pragma unroll
                for (int nt = 0; nt < 2; ++nt) {
                    int col = w * 32 + nt * 16 + l15;
                    atomicAdd(ag + col, acc2[mt][nt][r] + b2v[nt]);
                }
            }
        }
        __syncthreads();
    }
}

// ---------------------------------------------------------------------------
__device__ __forceinline__ float sigmoidf_(float x) { return 1.f / (1.f + expf(-x)); }

// fused GRUCell + BatchNorm(eval) + residual, 8 nodes per block
__global__ __launch_bounds__(256) void k_gru(const float* __restrict__ agg,
                                             float* __restrict__ h,
                                             const float* __restrict__ wihT,  // [128][384]
                                             const float* __restrict__ whhT,  // [128][384]
                                             const float* __restrict__ bih,
                                             const float* __restrict__ bhh,
                                             const float* __restrict__ gamma,
                                             const float* __restrict__ beta,
                                             const float* __restrict__ mean,
                                             const float* __restrict__ var) {
    __shared__ float aggs[8][128];
    __shared__ float hs[8][128];
    const int t = threadIdx.x;
    const int n0 = blockIdx.x * 8;   // NN % 8 == 0

    ((float4*)&aggs[0][0])[t] = ((const float4*)(agg + (size_t)n0 * H))[t];
    ((float4*)&hs[0][0])[t]   = ((const float4*)(h   + (size_t)n0 * H))[t];
    __syncthreads();

    const int c = t & 127;
    const int g = t >> 7;   // node group: nodes g*4 .. g*4+3

    const float bi_r = bih[c], bi_z = bih[128 + c], bi_n = bih[256 + c];
    const float bh_r = bhh[c], bh_z = bhh[128 + c], bh_n = bhh[256 + c];
    float ir[4], iz[4], inn[4], hr[4], hz[4], hn[4];
    #pragma unroll
    for (int n = 0; n < 4; ++n) {
        ir[n] = bi_r; iz[n] = bi_z; inn[n] = bi_n;
        hr[n] = bh_r; hz[n] = bh_z; hn[n]  = bh_n;
    }

    #pragma unroll 2
    for (int k = 0; k < 128; ++k) {
        float wir = wihT[k * 384 + c];
        float wiz = wihT[k * 384 + 128 + c];
        float win = wihT[k * 384 + 256 + c];
        float whr = whhT[k * 384 + c];
        float whz = whhT[k * 384 + 128 + c];
        float whn = whhT[k * 384 + 256 + c];
        #pragma unroll
        for (int n = 0; n < 4; ++n) {
            float a  = aggs[g * 4 + n][k];
            float hv = hs[g * 4 + n][k];
            ir[n]  += a * wir;  iz[n] += a * wiz;  inn[n] += a * win;
            hr[n]  += hv * whr; hz[n] += hv * whz; hn[n]  += hv * whn;
        }
    }

    const float ga = gamma[c], be = beta[c], mu = mean[c];
    const float iv = rsqrtf(var[c] + 1e-5f);
    #pragma unroll
    for (int n = 0; n < 4; ++n) {
        int node = n0 + g * 4 + n;
        float r  = sigmoidf_(ir[n] + hr[n]);
        float z  = sigmoidf_(iz[n] + hz[n]);
        float nn = tanhf(inn[n] + r * hn[n]);
        float hv = hs[g * 4 + n][c];
        float hnew = (1.f - z) * nn + z * hv;
        float bn = (hnew - mu) * iv * ga + be;
        h[(size_t)node * H + c] = hv + bn;
    }
}

// ---------------------------------------------------------------------------
// readout
__device__ __forceinline__ unsigned fkey(float f) {
    unsigned b = __float_as_uint(f);
    return (b & 0x80000000u) ? ~b : (b | 0x80000000u);
}
__device__ __forceinline__ float funkey(unsigned k) {
    unsigned b = (k & 0x80000000u) ? (k & 0x7FFFFFFFu) : ~k;
    return __uint_as_float(b);
}

__global__ __launch_bounds__(256) void k_ro_init(float* __restrict__ gsum,
                                                 unsigned* __restrict__ gmaxb,
                                                 float* __restrict__ gcnt) {
    int i = blockIdx.x * 256 + threadIdx.x;
    if (i < NG * H) { gsum[i] = 0.f; gmaxb[i] = 0u; }
    if (i < NG) gcnt[i] = 0.f;
}

__global__ __launch_bounds__(256) void k_scatter(const float* __restrict__ h,
                                                 const int* __restrict__ batch,
                                                 float* __restrict__ gsum,
                                                 unsigned* __restrict__ gmaxb,
                                                 float* __restrict__ gcnt) {
    int idx = blockIdx.x * 256 + threadIdx.x;   // NN*H
    if (idx >= NN * H) return;
    int n = idx >> 7, c = idx & 127;
    int g = batch[n];
    float v = h[idx];
    atomicAdd(&gsum[g * H + c], v);
    atomicMax(&gmaxb[g * H + c], fkey(v));
    if (c == 0) atomicAdd(&gcnt[g], 1.f);
}

__global__ __launch_bounds__(128) void k_ro_final(const float* __restrict__ gsum,
                                                  const unsigned* __restrict__ gmaxb,
                                                  const float* __restrict__ gcnt,
                                                  const float* __restrict__ row,
                                                  const float* __restrict__ rob,
                                                  float* __restrict__ out) {
    __shared__ float cat[256];
    const int g = blockIdx.x, t = threadIdx.x;
    float cnt = gcnt[g];
    float inv = 1.f / fmaxf(cnt, 1.f);
    cat[t] = gsum[g * H + t] * inv;
    float mx = funkey(gmaxb[g * H + t]);
    cat[128 + t] = (cnt > 0.f) ? mx : 0.f;
    __syncthreads();
    float acc = rob[t];
    #pragma unroll 4
    for (int k = 0; k < 256; ++k) acc += cat[k] * row[k * H + t];
    out[g * H + t] = fmaxf(acc, 0.f);
}

// ---------------------------------------------------------------------------
extern "C" void kernel_launch(void* const* d_in, const int* in_sizes, int n_in,
                              void* d_out, int out_size, void* d_ws, size_t ws_size,
                              hipStream_t stream) {
    const float* x        = (const float*)d_in[0];
    const int*   ei       = (const int*)d_in[1];
    const float* ea       = (const float*)d_in[2];
    const int*   batch    = (const int*)d_in[3];
    const float* lin_in_w = (const float*)d_in[5];
    const float* lin_in_b = (const float*)d_in[6];
    const float* msg_w1   = (const float*)d_in[7];
    const float* msg_b1   = (const float*)d_in[8];
    const float* msg_w2   = (const float*)d_in[9];
    const float* msg_b2   = (const float*)d_in[10];
    const float* bn_gamma = (const float*)d_in[11];
    const float* bn_beta  = (const float*)d_in[12];
    const float* bn_mean  = (const float*)d_in[13];
    const float* bn_var   = (const float*)d_in[14];
    const float* gru_wih  = (const float*)d_in[15];
    const float* gru_whh  = (const float*)d_in[16];
    const float* gru_bih  = (const float*)d_in[17];
    const float* gru_bhh  = (const float*)d_in[18];
    const float* ro_w     = (const float*)d_in[19];
    const float* ro_b     = (const float*)d_in[20];

    float* ws = (float*)d_ws;
    float*          h     = ws;                        // 6,400,000 f
    float*          agg   = ws + 6400000;              // 6,400,000 f
    unsigned short* p_bf  = (unsigned short*)(ws + 12800000);  // 6.4M bf16 (3.2M f)
    float*          gsum  = ws + 16000000;             // 32,768 f
    unsigned*       gmaxb = (unsigned*)(ws + 16032768);// 32,768
    float*          gcnt  = ws + 16065536;             // 256
    float*          wT    = ws + 16065792;             // 294,912 f
    unsigned short* w1et  = (unsigned short*)(ws + 16360704); // 12,288 bf16
    unsigned short* w2t   = (unsigned short*)(ws + 16366848); // 49,152 bf16
    // total ~65.6 MB

    // one-time (per launch) weight prep
    k_transpose<<<1152, 256, 0, stream>>>(gru_wih, gru_whh, wT);
    k_prep<<<240, 256, 0, stream>>>(msg_w1, msg_w2, w1et, w2t);

    // input projection: h = relu(x @ Win + b)
    k_gemm128<true, true, false><<<1563, 256, 0, stream>>>(x, lin_in_w, lin_in_b, h, nullptr, NN);

    for (int l = 0; l < NL; ++l) {
        const float* w1 = msg_w1 + (size_t)l * 144 * 128;
        // p_bf = bf16(h @ W1[:128,:])
        k_gemm128<false, false, true><<<1563, 256, 0, stream>>>(h, w1, nullptr, nullptr, p_bf, NN);
        // agg = 0
        k_zero4<<<6250, 256, 0, stream>>>((float4*)agg, 1600000);
        // edge MLP (MFMA) + scatter-add
        k_edge_mfma<<<768, 256, 0, stream>>>(p_bf, ea, ei,
                                             w1et + (size_t)l * 4096, msg_b1 + l * 128,
                                             w2t + (size_t)l * 16384, msg_b2 + l * 128,
                                             agg);
        // GRU + BN + residual
        k_gru<<<6250, 256, 0, stream>>>(agg, h,
                                        wT + (size_t)l * 49152,
                                        wT + (size_t)(NL + l) * 49152,
                                        gru_bih + l * 384, gru_bhh + l * 384,
                                        bn_gamma + l * 128, bn_beta + l * 128,
                                        bn_mean + l * 128, bn_var + l * 128);
    }

    // readout
    k_ro_init<<<128, 256, 0, stream>>>(gsum, gmaxb, gcnt);
    k_scatter<<<25000, 256, 0, stream>>>(h, batch, gsum, gmaxb, gcnt);
    k_ro_final<<<NG, 128, 0, stream>>>(gsum, gmaxb, gcnt, ro_w, ro_b, (float*)d_out);
}

// Round 3
// 1662.257 us; speedup vs baseline: 2.2665x; 1.2753x over previous
//
#include <hip/hip_runtime.h>
#include <math.h>

// Problem constants (from reference)
constexpr int NN = 50000;     // nodes
constexpr int NE = 800000;    // edges
constexpr int H  = 128;       // hidden
constexpr int ED = 16;        // edge dim
constexpr int NL = 3;         // layers
constexpr int NG = 256;       // graphs

typedef __attribute__((ext_vector_type(8))) short bf8;    // 8 bf16 in 4 VGPRs
typedef __attribute__((ext_vector_type(4))) float f32x4;  // MFMA accumulator

__device__ __forceinline__ unsigned short f2bf(float f) {
    unsigned u = __float_as_uint(f);
    unsigned r = (u + 0x7FFFu + ((u >> 16) & 1u)) >> 16;   // RNE
    return (unsigned short)r;
}
__device__ __forceinline__ float bf2f(unsigned short b) {
    return __uint_as_float(((unsigned)b) << 16);
}

// ---------------------------------------------------------------------------
__global__ __launch_bounds__(256) void k_zero4(float4* __restrict__ a, int n4) {
    int i = blockIdx.x * 256 + threadIdx.x;
    if (i < n4) a[i] = make_float4(0.f, 0.f, 0.f, 0.f);
}

// ---------------------------------------------------------------------------
// bf16 weight prep (all layouts MFMA-B-ready: [n][k])
//  wgru_bf[m][l][n384][k128] = w_m[l][n][k]          (straight convert)
//  w1et[l][n128][k32]  = msg_w1[l][128+k][n] (k<16 else 0)
//  w2t [l][n128][k128] = msg_w2[l][k][n]
//  w1ht[l][n128][k128] = msg_w1[l][k][n]
//  winT[n128][k128]    = lin_in_w[k][n]
__global__ __launch_bounds__(256) void k_prep(const float* __restrict__ wih,
                                              const float* __restrict__ whh,
                                              const float* __restrict__ w1,
                                              const float* __restrict__ w2,
                                              const float* __restrict__ lin_w,
                                              unsigned short* __restrict__ wgru,
                                              unsigned short* __restrict__ w1et,
                                              unsigned short* __restrict__ w2t,
                                              unsigned short* __restrict__ w1ht,
                                              unsigned short* __restrict__ winT) {
    int i = blockIdx.x * 256 + threadIdx.x;
    if (i < 294912) {                     // gru weights, flat convert
        int m = i / 147456, rem = i % 147456;
        wgru[i] = f2bf((m == 0 ? wih : whh)[rem]);
        return;
    }
    i -= 294912;
    if (i < NL * 128 * 32) {              // w1 edge part, transposed, padded
        int l = i / 4096, rem = i % 4096;
        int n = rem >> 5, k = rem & 31;
        float v = (k < ED) ? w1[(size_t)l * 144 * 128 + (size_t)(128 + k) * 128 + n] : 0.f;
        w1et[i] = f2bf(v);
        return;
    }
    i -= NL * 128 * 32;
    if (i < NL * 128 * 128) {             // w2 transposed
        int l = i / 16384, rem = i % 16384;
        int n = rem >> 7, k = rem & 127;
        w2t[i] = f2bf(w2[(size_t)l * 16384 + (size_t)k * 128 + n]);
        return;
    }
    i -= NL * 128 * 128;
    if (i < NL * 128 * 128) {             // w1 node part, transposed
        int l = i / 16384, rem = i % 16384;
        int n = rem >> 7, k = rem & 127;
        w1ht[i] = f2bf(w1[(size_t)l * 144 * 128 + (size_t)k * 128 + n]);
        return;
    }
    i -= NL * 128 * 128;
    if (i < 128 * 128) {                  // lin_in_w transposed
        int n = i >> 7, k = i & 127;
        winT[i] = f2bf(lin_w[k * 128 + n]);
    }
}

// ---------------------------------------------------------------------------
// MFMA GEMM: C[M,128] = act(A[M,128] @ B + bias), B given as [n][k] bf16.
// 32 rows per block; wave w owns cols [w*32, w*32+32); B-frags in registers.
template <bool A_F32, bool RELU, bool BIAS, bool OUT_F32>
__global__ __launch_bounds__(256) void k_mfma_gemm(const float* __restrict__ A_f,
                                                   const unsigned short* __restrict__ A_bf,
                                                   const unsigned short* __restrict__ Bt,
                                                   const float* __restrict__ bias,
                                                   float* __restrict__ C_f,
                                                   unsigned short* __restrict__ C_bf,
                                                   int M) {
    __shared__ unsigned short As[32][136];
    const int t = threadIdx.x;
    const int w = t >> 6, lane = t & 63, l15 = lane & 15, q = lane >> 4;
    const int n0 = blockIdx.x * 32;

    // B fragments (per wave: 2 col-tiles x 4 k-steps)
    bf8 bfr[2][4];
    #pragma unroll
    for (int nt = 0; nt < 2; ++nt) {
        int n = w * 32 + nt * 16 + l15;
        #pragma unroll
        for (int ks = 0; ks < 4; ++ks)
            bfr[nt][ks] = *(const bf8*)(Bt + (size_t)n * 128 + ks * 32 + q * 8);
    }

    // stage A tile as bf16 (row r = t>>3, col segment (t&7)*16)
    {
        int r = t >> 3, cs = (t & 7) * 16;
        int row = n0 + r;
        union { uint4 u[2]; unsigned short s[16]; } pk;
        if (A_F32) {
            float4 v[4];
            if (row < M) {
                const float4* src = (const float4*)(A_f + (size_t)row * H + cs);
                v[0] = src[0]; v[1] = src[1]; v[2] = src[2]; v[3] = src[3];
            } else {
                v[0] = v[1] = v[2] = v[3] = make_float4(0.f, 0.f, 0.f, 0.f);
            }
            #pragma unroll
            for (int j = 0; j < 4; ++j) {
                pk.s[j * 4 + 0] = f2bf(v[j].x); pk.s[j * 4 + 1] = f2bf(v[j].y);
                pk.s[j * 4 + 2] = f2bf(v[j].z); pk.s[j * 4 + 3] = f2bf(v[j].w);
            }
        } else {
            if (row < M) {
                const uint4* src = (const uint4*)(A_bf + (size_t)row * H + cs);
                pk.u[0] = src[0]; pk.u[1] = src[1];
            } else {
                pk.u[0] = pk.u[1] = make_uint4(0, 0, 0, 0);
            }
        }
        *(uint4*)&As[r][cs] = pk.u[0];
        *(uint4*)&As[r][cs + 8] = pk.u[1];
    }
    __syncthreads();

    f32x4 acc[2][2];
    #pragma unroll
    for (int mt = 0; mt < 2; ++mt)
        #pragma unroll
        for (int nt = 0; nt < 2; ++nt) acc[mt][nt] = {0.f, 0.f, 0.f, 0.f};

    #pragma unroll
    for (int ks = 0; ks < 4; ++ks) {
        #pragma unroll
        for (int mt = 0; mt < 2; ++mt) {
            bf8 af = *(const bf8*)&As[mt * 16 + l15][ks * 32 + q * 8];
            acc[mt][0] = __builtin_amdgcn_mfma_f32_16x16x32_bf16(af, bfr[0][ks], acc[mt][0], 0, 0, 0);
            acc[mt][1] = __builtin_amdgcn_mfma_f32_16x16x32_bf16(af, bfr[1][ks], acc[mt][1], 0, 0, 0);
        }
    }

    #pragma unroll
    for (int nt = 0; nt < 2; ++nt) {
        int col = w * 32 + nt * 16 + l15;
        float bv = BIAS ? bias[col] : 0.f;
        #pragma unroll
        for (int mt = 0; mt < 2; ++mt) {
            #pragma unroll
            for (int r = 0; r < 4; ++r) {
                int node = n0 + mt * 16 + q * 4 + r;
                if (node < M) {
                    float v = acc[mt][nt][r] + bv;
                    if (RELU) v = fmaxf(v, 0.f);
                    if (OUT_F32) C_f[(size_t)node * H + col] = v;
                    C_bf[(size_t)node * H + col] = f2bf(v);
                }
            }
        }
    }
}

// ---------------------------------------------------------------------------
// MFMA edge kernel (same as round 2, higher occupancy).
__global__ __launch_bounds__(256, 6) void k_edge_mfma(
        const unsigned short* __restrict__ p,     // [NN][128] bf16
        const float* __restrict__ ea,             // [NE][16]
        const int* __restrict__ ei,               // [2][NE]
        const unsigned short* __restrict__ w1et,  // [128][32] bf16
        const float* __restrict__ b1,
        const unsigned short* __restrict__ w2t,   // [128][128] bf16
        const float* __restrict__ b2,
        float* __restrict__ agg) {
    __shared__ unsigned short hid_s[64][136];
    __shared__ int src_s[64], dst_s[64];

    const int t    = threadIdx.x;
    const int w    = t >> 6;
    const int lane = t & 63;
    const int l15  = lane & 15;
    const int q    = lane >> 4;

    bf8 w1f[2];
    bf8 w2f[2][4];
    float b1v[2], b2v[2];
    #pragma unroll
    for (int nt = 0; nt < 2; ++nt) {
        int n = w * 32 + nt * 16 + l15;
        w1f[nt] = *(const bf8*)(w1et + (size_t)n * 32 + q * 8);
        #pragma unroll
        for (int ks = 0; ks < 4; ++ks)
            w2f[nt][ks] = *(const bf8*)(w2t + (size_t)n * 128 + ks * 32 + q * 8);
        b1v[nt] = b1[n];
        b2v[nt] = b2[n];
    }

    const f32x4 zero = {0.f, 0.f, 0.f, 0.f};

    for (int base = blockIdx.x * 64; base < NE; base += gridDim.x * 64) {
        if (t < 64)       src_s[t] = ei[base + t];
        else if (t < 128) dst_s[t - 64] = ei[NE + base + (t - 64)];
        __syncthreads();

        // phase 1: hid = relu(p[src] + ea@W1e + b1)
        f32x4 acc1[4][2];
        #pragma unroll
        for (int mt = 0; mt < 4; ++mt) {
            bf8 af = {0, 0, 0, 0, 0, 0, 0, 0};
            if (q < 2) {
                const float4* e4 = (const float4*)(ea + (size_t)(base + mt * 16 + l15) * ED + q * 8);
                float4 v0 = e4[0], v1 = e4[1];
                af[0] = (short)f2bf(v0.x); af[1] = (short)f2bf(v0.y);
                af[2] = (short)f2bf(v0.z); af[3] = (short)f2bf(v0.w);
                af[4] = (short)f2bf(v1.x); af[5] = (short)f2bf(v1.y);
                af[6] = (short)f2bf(v1.z); af[7] = (short)f2bf(v1.w);
            }
            #pragma unroll
            for (int nt = 0; nt < 2; ++nt)
                acc1[mt][nt] = __builtin_amdgcn_mfma_f32_16x16x32_bf16(af, w1f[nt], zero, 0, 0, 0);
        }
        #pragma unroll
        for (int mt = 0; mt < 4; ++mt) {
            #pragma unroll
            for (int r = 0; r < 4; ++r) {
                int er = mt * 16 + q * 4 + r;
                const unsigned short* prow = p + (size_t)src_s[er] * H;
                #pragma unroll
                for (int nt = 0; nt < 2; ++nt) {
                    int col = w * 32 + nt * 16 + l15;
                    float v = acc1[mt][nt][r] + bf2f(prow[col]) + b1v[nt];
                    hid_s[er][col] = f2bf(fmaxf(v, 0.f));
                }
            }
        }
        __syncthreads();

        // phase 2: m = hid@W2 (+b2), scatter-add
        f32x4 acc2[4][2];
        #pragma unroll
        for (int mt = 0; mt < 4; ++mt)
            #pragma unroll
            for (int nt = 0; nt < 2; ++nt) acc2[mt][nt] = zero;

        #pragma unroll
        for (int ks = 0; ks < 4; ++ks) {
            #pragma unroll
            for (int mt = 0; mt < 4; ++mt) {
                bf8 af = *(const bf8*)&hid_s[mt * 16 + l15][ks * 32 + q * 8];
                acc2[mt][0] = __builtin_amdgcn_mfma_f32_16x16x32_bf16(af, w2f[0][ks], acc2[mt][0], 0, 0, 0);
                acc2[mt][1] = __builtin_amdgcn_mfma_f32_16x16x32_bf16(af, w2f[1][ks], acc2[mt][1], 0, 0, 0);
            }
        }

        #pragma unroll
        for (int mt = 0; mt < 4; ++mt) {
            #pragma unroll
            for (int r = 0; r < 4; ++r) {
                int er = mt * 16 + q * 4 + r;
                float* ag = agg + (size_t)dst_s[er] * H;
                #pragma unroll
                for (int nt = 0; nt < 2; ++nt) {
                    int col = w * 32 + nt * 16 + l15;
                    atomicAdd(ag + col, acc2[mt][nt][r] + b2v[nt]);
                }
            }
        }
        __syncthreads();
    }
}

// ---------------------------------------------------------------------------
__device__ __forceinline__ float sigmoidf_(float x) { return 1.f / (1.f + expf(-x)); }

// MFMA GRU + BN + residual. 32 nodes/block; wave w owns cols [w*32,w*32+32)
// of each gate (r,z,n) for both gi and gh => 24 acc tiles (96 f32/lane).
__global__ __launch_bounds__(256) void k_gru_mfma(const float* __restrict__ agg,
                                                  float* __restrict__ h,
                                                  unsigned short* __restrict__ h_bf,
                                                  const unsigned short* __restrict__ wih,  // [384][128] bf16
                                                  const unsigned short* __restrict__ whh,  // [384][128] bf16
                                                  const float* __restrict__ bih,
                                                  const float* __restrict__ bhh,
                                                  const float* __restrict__ gamma,
                                                  const float* __restrict__ beta,
                                                  const float* __restrict__ mean,
                                                  const float* __restrict__ var) {
    __shared__ unsigned short ab[32][136];   // agg bf16
    __shared__ unsigned short hb[32][136];   // h bf16
    __shared__ float hf[32][132];            // h fp32 (epilogue)
    const int t = threadIdx.x;
    const int w = t >> 6, lane = t & 63, l15 = lane & 15, q = lane >> 4;
    const int n0 = blockIdx.x * 32;

    // stage tiles
    {
        int r = t >> 3, cs = (t & 7) * 16;
        int row = n0 + r;
        float4 va[4], vh[4];
        if (row < NN) {
            const float4* sa = (const float4*)(agg + (size_t)row * H + cs);
            const float4* sh = (const float4*)(h + (size_t)row * H + cs);
            #pragma unroll
            for (int j = 0; j < 4; ++j) { va[j] = sa[j]; vh[j] = sh[j]; }
        } else {
            #pragma unroll
            for (int j = 0; j < 4; ++j) {
                va[j] = make_float4(0.f, 0.f, 0.f, 0.f);
                vh[j] = va[j];
            }
        }
        union { uint4 u[2]; unsigned short s[16]; } pa, ph;
        #pragma unroll
        for (int j = 0; j < 4; ++j) {
            pa.s[j * 4 + 0] = f2bf(va[j].x); pa.s[j * 4 + 1] = f2bf(va[j].y);
            pa.s[j * 4 + 2] = f2bf(va[j].z); pa.s[j * 4 + 3] = f2bf(va[j].w);
            ph.s[j * 4 + 0] = f2bf(vh[j].x); ph.s[j * 4 + 1] = f2bf(vh[j].y);
            ph.s[j * 4 + 2] = f2bf(vh[j].z); ph.s[j * 4 + 3] = f2bf(vh[j].w);
            *(float4*)&hf[r][cs + j * 4] = vh[j];
        }
        *(uint4*)&ab[r][cs] = pa.u[0];  *(uint4*)&ab[r][cs + 8] = pa.u[1];
        *(uint4*)&hb[r][cs] = ph.u[0];  *(uint4*)&hb[r][cs + 8] = ph.u[1];
    }
    __syncthreads();

    // acc[mt][io][gate][nt]  io: 0 = gi(agg@wih), 1 = gh(h@whh)
    f32x4 acc[2][2][3][2];
    #pragma unroll
    for (int mt = 0; mt < 2; ++mt)
        #pragma unroll
        for (int io = 0; io < 2; ++io)
            #pragma unroll
            for (int g = 0; g < 3; ++g)
                #pragma unroll
                for (int nt = 0; nt < 2; ++nt) acc[mt][io][g][nt] = {0.f, 0.f, 0.f, 0.f};

    #pragma unroll
    for (int ks = 0; ks < 4; ++ks) {
        bf8 a_a[2], a_h[2];
        #pragma unroll
        for (int mt = 0; mt < 2; ++mt) {
            a_a[mt] = *(const bf8*)&ab[mt * 16 + l15][ks * 32 + q * 8];
            a_h[mt] = *(const bf8*)&hb[mt * 16 + l15][ks * 32 + q * 8];
        }
        #pragma unroll
        for (int g = 0; g < 3; ++g) {
            #pragma unroll
            for (int nt = 0; nt < 2; ++nt) {
                int n = g * 128 + w * 32 + nt * 16 + l15;
                bf8 bi = *(const bf8*)(wih + (size_t)n * 128 + ks * 32 + q * 8);
                bf8 bh = *(const bf8*)(whh + (size_t)n * 128 + ks * 32 + q * 8);
                #pragma unroll
                for (int mt = 0; mt < 2; ++mt) {
                    acc[mt][0][g][nt] = __builtin_amdgcn_mfma_f32_16x16x32_bf16(a_a[mt], bi, acc[mt][0][g][nt], 0, 0, 0);
                    acc[mt][1][g][nt] = __builtin_amdgcn_mfma_f32_16x16x32_bf16(a_h[mt], bh, acc[mt][1][g][nt], 0, 0, 0);
                }
            }
        }
    }

    #pragma unroll
    for (int nt = 0; nt < 2; ++nt) {
        int col = w * 32 + nt * 16 + l15;
        float bir = bih[col], biz = bih[128 + col], bin = bih[256 + col];
        float bhr = bhh[col], bhz = bhh[128 + col], bhn = bhh[256 + col];
        float ga = gamma[col], be = beta[col], mu = mean[col];
        float iv = rsqrtf(var[col] + 1e-5f);
        #pragma unroll
        for (int mt = 0; mt < 2; ++mt) {
            #pragma unroll
            for (int r = 0; r < 4; ++r) {
                int nl = mt * 16 + q * 4 + r;
                int node = n0 + nl;
                if (node < NN) {
                    float ir = acc[mt][0][0][nt][r] + bir;
                    float iz = acc[mt][0][1][nt][r] + biz;
                    float in = acc[mt][0][2][nt][r] + bin;
                    float hr = acc[mt][1][0][nt][r] + bhr;
                    float hz = acc[mt][1][1][nt][r] + bhz;
                    float hn = acc[mt][1][2][nt][r] + bhn;
                    float rg = sigmoidf_(ir + hr);
                    float zg = sigmoidf_(iz + hz);
                    float ng = tanhf(in + rg * hn);
                    float hv = hf[nl][col];
                    float hnew = (1.f - zg) * ng + zg * hv;
                    float bn = (hnew - mu) * iv * ga + be;
                    float out = hv + bn;
                    h[(size_t)node * H + col] = out;
                    h_bf[(size_t)node * H + col] = f2bf(out);
                }
            }
        }
    }
}

// ---------------------------------------------------------------------------
// readout
__device__ __forceinline__ unsigned fkey(float f) {
    unsigned b = __float_as_uint(f);
    return (b & 0x80000000u) ? ~b : (b | 0x80000000u);
}
__device__ __forceinline__ float funkey(unsigned k) {
    unsigned b = (k & 0x80000000u) ? (k & 0x7FFFFFFFu) : ~k;
    return __uint_as_float(b);
}

__global__ __launch_bounds__(256) void k_ro_init(float* __restrict__ gsum,
                                                 unsigned* __restrict__ gmaxb,
                                                 float* __restrict__ gcnt) {
    int i = blockIdx.x * 256 + threadIdx.x;
    if (i < NG * H) { gsum[i] = 0.f; gmaxb[i] = 0u; }
    if (i < NG) gcnt[i] = 0.f;
}

__global__ __launch_bounds__(256) void k_scatter(const float* __restrict__ h,
                                                 const int* __restrict__ batch,
                                                 float* __restrict__ gsum,
                                                 unsigned* __restrict__ gmaxb,
                                                 float* __restrict__ gcnt) {
    int idx = blockIdx.x * 256 + threadIdx.x;   // NN*H
    if (idx >= NN * H) return;
    int n = idx >> 7, c = idx & 127;
    int g = batch[n];
    float v = h[idx];
    atomicAdd(&gsum[g * H + c], v);
    atomicMax(&gmaxb[g * H + c], fkey(v));
    if (c == 0) atomicAdd(&gcnt[g], 1.f);
}

__global__ __launch_bounds__(128) void k_ro_final(const float* __restrict__ gsum,
                                                  const unsigned* __restrict__ gmaxb,
                                                  const float* __restrict__ gcnt,
                                                  const float* __restrict__ row,
                                                  const float* __restrict__ rob,
                                                  float* __restrict__ out) {
    __shared__ float cat[256];
    const int g = blockIdx.x, t = threadIdx.x;
    float cnt = gcnt[g];
    float inv = 1.f / fmaxf(cnt, 1.f);
    cat[t] = gsum[g * H + t] * inv;
    float mx = funkey(gmaxb[g * H + t]);
    cat[128 + t] = (cnt > 0.f) ? mx : 0.f;
    __syncthreads();
    float acc = rob[t];
    #pragma unroll 4
    for (int k = 0; k < 256; ++k) acc += cat[k] * row[k * H + t];
    out[g * H + t] = fmaxf(acc, 0.f);
}

// ---------------------------------------------------------------------------
extern "C" void kernel_launch(void* const* d_in, const int* in_sizes, int n_in,
                              void* d_out, int out_size, void* d_ws, size_t ws_size,
                              hipStream_t stream) {
    const float* x        = (const float*)d_in[0];
    const int*   ei       = (const int*)d_in[1];
    const float* ea       = (const float*)d_in[2];
    const int*   batch    = (const int*)d_in[3];
    const float* lin_in_w = (const float*)d_in[5];
    const float* lin_in_b = (const float*)d_in[6];
    const float* msg_w1   = (const float*)d_in[7];
    const float* msg_b1   = (const float*)d_in[8];
    const float* msg_w2   = (const float*)d_in[9];
    const float* msg_b2   = (const float*)d_in[10];
    const float* bn_gamma = (const float*)d_in[11];
    const float* bn_beta  = (const float*)d_in[12];
    const float* bn_mean  = (const float*)d_in[13];
    const float* bn_var   = (const float*)d_in[14];
    const float* gru_wih  = (const float*)d_in[15];
    const float* gru_whh  = (const float*)d_in[16];
    const float* gru_bih  = (const float*)d_in[17];
    const float* gru_bhh  = (const float*)d_in[18];
    const float* ro_w     = (const float*)d_in[19];
    const float* ro_b     = (const float*)d_in[20];

    float* ws = (float*)d_ws;
    float*          h     = ws;                                 // 6.4M f
    float*          agg   = ws + 6400000;                       // 6.4M f
    unsigned short* h_bf  = (unsigned short*)(ws + 12800000);   // 6.4M bf16
    unsigned short* p_bf  = (unsigned short*)(ws + 16000000);   // 6.4M bf16
    float*          gsum  = ws + 19200000;
    unsigned*       gmaxb = (unsigned*)(ws + 19232768);
    float*          gcnt  = ws + 19265536;
    unsigned short* wgru  = (unsigned short*)(ws + 19265792);   // 294,912 bf16
    unsigned short* w1et  = (unsigned short*)(ws + 19413248);   // 12,288 bf16
    unsigned short* w2t   = (unsigned short*)(ws + 19419392);   // 49,152 bf16
    unsigned short* w1ht  = (unsigned short*)(ws + 19443968);   // 49,152 bf16
    unsigned short* winT  = (unsigned short*)(ws + 19468544);   // 16,384 bf16
    // end: 19,476,736 floats (~77.9 MB)

    // weight prep (bf16, B-layout)
    k_prep<<<1648, 256, 0, stream>>>(gru_wih, gru_whh, msg_w1, msg_w2, lin_in_w,
                                     wgru, w1et, w2t, w1ht, winT);

    // input projection: h = relu(x @ Win + b)  (fp32 + bf16 outputs)
    k_mfma_gemm<true, true, true, true><<<1563, 256, 0, stream>>>(
        x, nullptr, winT, lin_in_b, h, h_bf, NN);

    for (int l = 0; l < NL; ++l) {
        // p_bf = bf16(h_bf @ W1h^T)
        k_mfma_gemm<false, false, false, false><<<1563, 256, 0, stream>>>(
            nullptr, h_bf, w1ht + (size_t)l * 16384, nullptr, nullptr, p_bf, NN);
        // agg = 0
        k_zero4<<<6250, 256, 0, stream>>>((float4*)agg, 1600000);
        // edge MLP (MFMA) + scatter-add
        k_edge_mfma<<<1536, 256, 0, stream>>>(p_bf, ea, ei,
                                              w1et + (size_t)l * 4096, msg_b1 + l * 128,
                                              w2t + (size_t)l * 16384, msg_b2 + l * 128,
                                              agg);
        // GRU + BN + residual (MFMA)
        k_gru_mfma<<<1563, 256, 0, stream>>>(agg, h, h_bf,
                                             wgru + (size_t)l * 49152,
                                             wgru + (size_t)(NL + l) * 49152,
                                             gru_bih + l * 384, gru_bhh + l * 384,
                                             bn_gamma + l * 128, bn_beta + l * 128,
                                             bn_mean + l * 128, bn_var + l * 128);
    }

    // readout
    k_ro_init<<<128, 256, 0, stream>>>(gsum, gmaxb, gcnt);
    k_scatter<<<25000, 256, 0, stream>>>(h, batch, gsum, gmaxb, gcnt);
    k_ro_final<<<NG, 128, 0, stream>>>(gsum, gmaxb, gcnt, ro_w, ro_b, (float*)d_out);
}

// Round 4
// 862.929 us; speedup vs baseline: 4.3659x; 1.9263x over previous
//
#include <hip/hip_runtime.h>
#include <math.h>

// Problem constants (from reference)
constexpr int NN = 50000;     // nodes
constexpr int NE = 800000;    // edges
constexpr int H  = 128;       // hidden
constexpr int ED = 16;        // edge dim
constexpr int NL = 3;         // layers
constexpr int NG = 256;       // graphs
constexpr int NBINS = 50176;  // 196*256, >= NN

typedef __attribute__((ext_vector_type(8))) short bf8;    // 8 bf16 in 4 VGPRs
typedef __attribute__((ext_vector_type(4))) float f32x4;  // MFMA accumulator

__device__ __forceinline__ unsigned short f2bf(float f) {
    unsigned u = __float_as_uint(f);
    unsigned r = (u + 0x7FFFu + ((u >> 16) & 1u)) >> 16;   // RNE
    return (unsigned short)r;
}
__device__ __forceinline__ float bf2f(unsigned short b) {
    return __uint_as_float(((unsigned)b) << 16);
}

// ---------------------------------------------------------------------------
__global__ __launch_bounds__(256) void k_zero4(float4* __restrict__ a, int n4) {
    int i = blockIdx.x * 256 + threadIdx.x;
    if (i < n4) a[i] = make_float4(0.f, 0.f, 0.f, 0.f);
}

// ---------------------------------------------------------------------------
// counting sort of edges by dst -------------------------------------------
__global__ __launch_bounds__(256) void k_sort_zero(int* __restrict__ counts) {
    int i = blockIdx.x * 256 + threadIdx.x;   // grid 196
    counts[i] = 0;
}

__global__ __launch_bounds__(256) void k_hist(const int* __restrict__ ei,
                                              int* __restrict__ counts) {
    int e = blockIdx.x * 256 + threadIdx.x;
    if (e < NE) atomicAdd(&counts[ei[NE + e]], 1);
}

__global__ __launch_bounds__(256) void k_scan1(const int* __restrict__ counts,
                                               int* __restrict__ incl,
                                               int* __restrict__ bsum) {
    __shared__ int s[256];
    int t = threadIdx.x;
    int i = blockIdx.x * 256 + t;             // grid 196 -> i < 50176
    int v = counts[i];
    s[t] = v;
    __syncthreads();
    #pragma unroll
    for (int off = 1; off < 256; off <<= 1) {
        int x = (t >= off) ? s[t - off] : 0;
        __syncthreads();
        s[t] += x;
        __syncthreads();
    }
    incl[i] = s[t];
    if (t == 255) bsum[blockIdx.x] = s[255];
}

__global__ __launch_bounds__(256) void k_scan2(int* __restrict__ bsum) {
    __shared__ int s[256];
    int t = threadIdx.x;
    int v = (t < 196) ? bsum[t] : 0;
    s[t] = v;
    __syncthreads();
    #pragma unroll
    for (int off = 1; off < 256; off <<= 1) {
        int x = (t >= off) ? s[t - off] : 0;
        __syncthreads();
        s[t] += x;
        __syncthreads();
    }
    if (t < 196) bsum[t] = s[t] - v;          // exclusive
}

__global__ __launch_bounds__(256) void k_scan3(const int* __restrict__ counts,
                                               const int* __restrict__ incl,
                                               const int* __restrict__ bsum,
                                               int* __restrict__ cur) {
    int i = blockIdx.x * 256 + threadIdx.x;   // grid 196
    cur[i] = incl[i] - counts[i] + bsum[blockIdx.x];
}

__global__ __launch_bounds__(256) void k_scatter_perm(const int* __restrict__ ei,
                                                      int* __restrict__ cur,
                                                      int* __restrict__ perm) {
    int e = blockIdx.x * 256 + threadIdx.x;
    if (e < NE) {
        int d = ei[NE + e];
        int pos = atomicAdd(&cur[d], 1);
        perm[pos] = e;
    }
}

// ---------------------------------------------------------------------------
// bf16 weight prep (all layouts MFMA-B-ready: [n][k])
__global__ __launch_bounds__(256) void k_prep(const float* __restrict__ wih,
                                              const float* __restrict__ whh,
                                              const float* __restrict__ w1,
                                              const float* __restrict__ w2,
                                              const float* __restrict__ lin_w,
                                              unsigned short* __restrict__ wgru,
                                              unsigned short* __restrict__ w1et,
                                              unsigned short* __restrict__ w2t,
                                              unsigned short* __restrict__ w1ht,
                                              unsigned short* __restrict__ winT) {
    int i = blockIdx.x * 256 + threadIdx.x;
    if (i < 294912) {                     // gru weights, flat convert
        int m = i / 147456, rem = i % 147456;
        wgru[i] = f2bf((m == 0 ? wih : whh)[rem]);
        return;
    }
    i -= 294912;
    if (i < NL * 128 * 32) {              // w1 edge part, transposed, padded
        int l = i / 4096, rem = i % 4096;
        int n = rem >> 5, k = rem & 31;
        float v = (k < ED) ? w1[(size_t)l * 144 * 128 + (size_t)(128 + k) * 128 + n] : 0.f;
        w1et[i] = f2bf(v);
        return;
    }
    i -= NL * 128 * 32;
    if (i < NL * 128 * 128) {             // w2 transposed
        int l = i / 16384, rem = i % 16384;
        int n = rem >> 7, k = rem & 127;
        w2t[i] = f2bf(w2[(size_t)l * 16384 + (size_t)k * 128 + n]);
        return;
    }
    i -= NL * 128 * 128;
    if (i < NL * 128 * 128) {             // w1 node part, transposed
        int l = i / 16384, rem = i % 16384;
        int n = rem >> 7, k = rem & 127;
        w1ht[i] = f2bf(w1[(size_t)l * 144 * 128 + (size_t)k * 128 + n]);
        return;
    }
    i -= NL * 128 * 128;
    if (i < 128 * 128) {                  // lin_in_w transposed
        int n = i >> 7, k = i & 127;
        winT[i] = f2bf(lin_w[k * 128 + n]);
    }
}

// ---------------------------------------------------------------------------
// MFMA GEMM: C[M,128] = act(A[M,128] @ B + bias), B given as [n][k] bf16.
template <bool A_F32, bool RELU, bool BIAS, bool OUT_F32>
__global__ __launch_bounds__(256) void k_mfma_gemm(const float* __restrict__ A_f,
                                                   const unsigned short* __restrict__ A_bf,
                                                   const unsigned short* __restrict__ Bt,
                                                   const float* __restrict__ bias,
                                                   float* __restrict__ C_f,
                                                   unsigned short* __restrict__ C_bf,
                                                   int M) {
    __shared__ unsigned short As[32][136];
    const int t = threadIdx.x;
    const int w = t >> 6, lane = t & 63, l15 = lane & 15, q = lane >> 4;
    const int n0 = blockIdx.x * 32;

    bf8 bfr[2][4];
    #pragma unroll
    for (int nt = 0; nt < 2; ++nt) {
        int n = w * 32 + nt * 16 + l15;
        #pragma unroll
        for (int ks = 0; ks < 4; ++ks)
            bfr[nt][ks] = *(const bf8*)(Bt + (size_t)n * 128 + ks * 32 + q * 8);
    }

    {
        int r = t >> 3, cs = (t & 7) * 16;
        int row = n0 + r;
        union { uint4 u[2]; unsigned short s[16]; } pk;
        if (A_F32) {
            float4 v[4];
            if (row < M) {
                const float4* src = (const float4*)(A_f + (size_t)row * H + cs);
                v[0] = src[0]; v[1] = src[1]; v[2] = src[2]; v[3] = src[3];
            } else {
                v[0] = v[1] = v[2] = v[3] = make_float4(0.f, 0.f, 0.f, 0.f);
            }
            #pragma unroll
            for (int j = 0; j < 4; ++j) {
                pk.s[j * 4 + 0] = f2bf(v[j].x); pk.s[j * 4 + 1] = f2bf(v[j].y);
                pk.s[j * 4 + 2] = f2bf(v[j].z); pk.s[j * 4 + 3] = f2bf(v[j].w);
            }
        } else {
            if (row < M) {
                const uint4* src = (const uint4*)(A_bf + (size_t)row * H + cs);
                pk.u[0] = src[0]; pk.u[1] = src[1];
            } else {
                pk.u[0] = pk.u[1] = make_uint4(0, 0, 0, 0);
            }
        }
        *(uint4*)&As[r][cs] = pk.u[0];
        *(uint4*)&As[r][cs + 8] = pk.u[1];
    }
    __syncthreads();

    f32x4 acc[2][2];
    #pragma unroll
    for (int mt = 0; mt < 2; ++mt)
        #pragma unroll
        for (int nt = 0; nt < 2; ++nt) acc[mt][nt] = {0.f, 0.f, 0.f, 0.f};

    #pragma unroll
    for (int ks = 0; ks < 4; ++ks) {
        #pragma unroll
        for (int mt = 0; mt < 2; ++mt) {
            bf8 af = *(const bf8*)&As[mt * 16 + l15][ks * 32 + q * 8];
            acc[mt][0] = __builtin_amdgcn_mfma_f32_16x16x32_bf16(af, bfr[0][ks], acc[mt][0], 0, 0, 0);
            acc[mt][1] = __builtin_amdgcn_mfma_f32_16x16x32_bf16(af, bfr[1][ks], acc[mt][1], 0, 0, 0);
        }
    }

    #pragma unroll
    for (int nt = 0; nt < 2; ++nt) {
        int col = w * 32 + nt * 16 + l15;
        float bv = BIAS ? bias[col] : 0.f;
        #pragma unroll
        for (int mt = 0; mt < 2; ++mt) {
            #pragma unroll
            for (int r = 0; r < 4; ++r) {
                int node = n0 + mt * 16 + q * 4 + r;
                if (node < M) {
                    float v = acc[mt][nt][r] + bv;
                    if (RELU) v = fmaxf(v, 0.f);
                    if (OUT_F32) C_f[(size_t)node * H + col] = v;
                    C_bf[(size_t)node * H + col] = f2bf(v);
                }
            }
        }
    }
}

// ---------------------------------------------------------------------------
// MFMA edge kernel over dst-sorted edges (perm). Per 64-edge tile:
//   phase1: hid = relu(p[src] + ea@W1e + b1)      (p staged via LDS uint4)
//   phase2: m = hid@W2 + b2 -> LDS (bf16)
//   reduce: per-column run-scan over sorted dst, one atomicAdd per run
__global__ __launch_bounds__(256, 4) void k_edge_mfma(
        const unsigned short* __restrict__ p,     // [NN][128] bf16
        const float* __restrict__ ea,             // [NE][16]
        const int* __restrict__ ei,               // [2][NE]
        const int* __restrict__ perm,             // [NE] dst-sorted edge ids
        const unsigned short* __restrict__ w1et,  // [128][32] bf16
        const float* __restrict__ b1,
        const unsigned short* __restrict__ w2t,   // [128][128] bf16
        const float* __restrict__ b2,
        float* __restrict__ agg) {
    __shared__ unsigned short hid_s[64][136];   // 17.4 KB
    __shared__ unsigned short pm_s[64][136];    // 17.4 KB (p staging, then m)
    __shared__ int src_s[64], dst_s[64], perm_s[64];

    const int t    = threadIdx.x;
    const int w    = t >> 6;
    const int lane = t & 63;
    const int l15  = lane & 15;
    const int q    = lane >> 4;

    bf8 w1f[2];
    bf8 w2f[2][4];
    float b1v[2], b2v[2];
    #pragma unroll
    for (int nt = 0; nt < 2; ++nt) {
        int n = w * 32 + nt * 16 + l15;
        w1f[nt] = *(const bf8*)(w1et + (size_t)n * 32 + q * 8);
        #pragma unroll
        for (int ks = 0; ks < 4; ++ks)
            w2f[nt][ks] = *(const bf8*)(w2t + (size_t)n * 128 + ks * 32 + q * 8);
        b1v[nt] = b1[n];
        b2v[nt] = b2[n];
    }

    const f32x4 zero = {0.f, 0.f, 0.f, 0.f};

    for (int base = blockIdx.x * 64; base < NE; base += gridDim.x * 64) {
        if (t < 64) {
            int e = perm[base + t];
            perm_s[t] = e;
            src_s[t]  = ei[e];
            dst_s[t]  = ei[NE + e];
        }
        __syncthreads();

        // stage p rows (uint4, coalesced 256B per row / 16 lanes)
        {
            int row = t >> 4, seg = t & 15;
            #pragma unroll
            for (int it = 0; it < 4; ++it, row += 16)
                *(uint4*)&pm_s[row][seg * 8] =
                    *(const uint4*)(p + (size_t)src_s[row] * H + seg * 8);
        }

        // phase 1 MFMA: ea@W1e
        f32x4 acc1[4][2];
        #pragma unroll
        for (int mt = 0; mt < 4; ++mt) {
            bf8 af = {0, 0, 0, 0, 0, 0, 0, 0};
            if (q < 2) {
                int e = perm_s[mt * 16 + l15];
                const float4* e4 = (const float4*)(ea + (size_t)e * ED + q * 8);
                float4 v0 = e4[0], v1 = e4[1];
                af[0] = (short)f2bf(v0.x); af[1] = (short)f2bf(v0.y);
                af[2] = (short)f2bf(v0.z); af[3] = (short)f2bf(v0.w);
                af[4] = (short)f2bf(v1.x); af[5] = (short)f2bf(v1.y);
                af[6] = (short)f2bf(v1.z); af[7] = (short)f2bf(v1.w);
            }
            #pragma unroll
            for (int nt = 0; nt < 2; ++nt)
                acc1[mt][nt] = __builtin_amdgcn_mfma_f32_16x16x32_bf16(af, w1f[nt], zero, 0, 0, 0);
        }
        __syncthreads();   // p staged

        // epilogue 1: hid = relu(acc1 + p + b1)
        #pragma unroll
        for (int mt = 0; mt < 4; ++mt) {
            #pragma unroll
            for (int r = 0; r < 4; ++r) {
                int er = mt * 16 + q * 4 + r;
                #pragma unroll
                for (int nt = 0; nt < 2; ++nt) {
                    int col = w * 32 + nt * 16 + l15;
                    float v = acc1[mt][nt][r] + bf2f(pm_s[er][col]) + b1v[nt];
                    hid_s[er][col] = f2bf(fmaxf(v, 0.f));
                }
            }
        }
        __syncthreads();   // hid ready, pm_s free

        // phase 2: m = hid@W2 + b2 -> pm_s
        f32x4 acc2[4][2];
        #pragma unroll
        for (int mt = 0; mt < 4; ++mt)
            #pragma unroll
            for (int nt = 0; nt < 2; ++nt) acc2[mt][nt] = zero;

        #pragma unroll
        for (int ks = 0; ks < 4; ++ks) {
            #pragma unroll
            for (int mt = 0; mt < 4; ++mt) {
                bf8 af = *(const bf8*)&hid_s[mt * 16 + l15][ks * 32 + q * 8];
                acc2[mt][0] = __builtin_amdgcn_mfma_f32_16x16x32_bf16(af, w2f[0][ks], acc2[mt][0], 0, 0, 0);
                acc2[mt][1] = __builtin_amdgcn_mfma_f32_16x16x32_bf16(af, w2f[1][ks], acc2[mt][1], 0, 0, 0);
            }
        }
        #pragma unroll
        for (int mt = 0; mt < 4; ++mt) {
            #pragma unroll
            for (int r = 0; r < 4; ++r) {
                int er = mt * 16 + q * 4 + r;
                #pragma unroll
                for (int nt = 0; nt < 2; ++nt) {
                    int col = w * 32 + nt * 16 + l15;
                    pm_s[er][col] = f2bf(acc2[mt][nt][r] + b2v[nt]);
                }
            }
        }
        __syncthreads();   // m ready

        // run-scan reduction: one atomic per (run, col)
        {
            int c = t & 127, hh = t >> 7;
            float sum = 0.f;
            int prev = dst_s[hh * 32];
            #pragma unroll 4
            for (int i = 0; i < 32; ++i) {
                int e = hh * 32 + i;
                int d = dst_s[e];
                float v = bf2f(pm_s[e][c]);
                if (d != prev) {
                    atomicAdd(&agg[(size_t)prev * H + c], sum);
                    sum = 0.f;
                    prev = d;
                }
                sum += v;
            }
            atomicAdd(&agg[(size_t)prev * H + c], sum);
        }
        __syncthreads();   // scan done before next tile overwrites LDS
    }
}

// ---------------------------------------------------------------------------
__device__ __forceinline__ float sigmoidf_(float x) { return 1.f / (1.f + expf(-x)); }

// MFMA GRU + BN + residual. 32 nodes/block.
__global__ __launch_bounds__(256) void k_gru_mfma(const float* __restrict__ agg,
                                                  float* __restrict__ h,
                                                  unsigned short* __restrict__ h_bf,
                                                  const unsigned short* __restrict__ wih,  // [384][128] bf16
                                                  const unsigned short* __restrict__ whh,  // [384][128] bf16
                                                  const float* __restrict__ bih,
                                                  const float* __restrict__ bhh,
                                                  const float* __restrict__ gamma,
                                                  const float* __restrict__ beta,
                                                  const float* __restrict__ mean,
                                                  const float* __restrict__ var) {
    __shared__ unsigned short ab[32][136];
    __shared__ unsigned short hb[32][136];
    __shared__ float hf[32][132];
    const int t = threadIdx.x;
    const int w = t >> 6, lane = t & 63, l15 = lane & 15, q = lane >> 4;
    const int n0 = blockIdx.x * 32;

    {
        int r = t >> 3, cs = (t & 7) * 16;
        int row = n0 + r;
        float4 va[4], vh[4];
        if (row < NN) {
            const float4* sa = (const float4*)(agg + (size_t)row * H + cs);
            const float4* sh = (const float4*)(h + (size_t)row * H + cs);
            #pragma unroll
            for (int j = 0; j < 4; ++j) { va[j] = sa[j]; vh[j] = sh[j]; }
        } else {
            #pragma unroll
            for (int j = 0; j < 4; ++j) {
                va[j] = make_float4(0.f, 0.f, 0.f, 0.f);
                vh[j] = va[j];
            }
        }
        union { uint4 u[2]; unsigned short s[16]; } pa, ph;
        #pragma unroll
        for (int j = 0; j < 4; ++j) {
            pa.s[j * 4 + 0] = f2bf(va[j].x); pa.s[j * 4 + 1] = f2bf(va[j].y);
            pa.s[j * 4 + 2] = f2bf(va[j].z); pa.s[j * 4 + 3] = f2bf(va[j].w);
            ph.s[j * 4 + 0] = f2bf(vh[j].x); ph.s[j * 4 + 1] = f2bf(vh[j].y);
            ph.s[j * 4 + 2] = f2bf(vh[j].z); ph.s[j * 4 + 3] = f2bf(vh[j].w);
            *(float4*)&hf[r][cs + j * 4] = vh[j];
        }
        *(uint4*)&ab[r][cs] = pa.u[0];  *(uint4*)&ab[r][cs + 8] = pa.u[1];
        *(uint4*)&hb[r][cs] = ph.u[0];  *(uint4*)&hb[r][cs + 8] = ph.u[1];
    }
    __syncthreads();

    f32x4 acc[2][2][3][2];
    #pragma unroll
    for (int mt = 0; mt < 2; ++mt)
        #pragma unroll
        for (int io = 0; io < 2; ++io)
            #pragma unroll
            for (int g = 0; g < 3; ++g)
                #pragma unroll
                for (int nt = 0; nt < 2; ++nt) acc[mt][io][g][nt] = {0.f, 0.f, 0.f, 0.f};

    #pragma unroll
    for (int ks = 0; ks < 4; ++ks) {
        bf8 a_a[2], a_h[2];
        #pragma unroll
        for (int mt = 0; mt < 2; ++mt) {
            a_a[mt] = *(const bf8*)&ab[mt * 16 + l15][ks * 32 + q * 8];
            a_h[mt] = *(const bf8*)&hb[mt * 16 + l15][ks * 32 + q * 8];
        }
        #pragma unroll
        for (int g = 0; g < 3; ++g) {
            #pragma unroll
            for (int nt = 0; nt < 2; ++nt) {
                int n = g * 128 + w * 32 + nt * 16 + l15;
                bf8 bi = *(const bf8*)(wih + (size_t)n * 128 + ks * 32 + q * 8);
                bf8 bh = *(const bf8*)(whh + (size_t)n * 128 + ks * 32 + q * 8);
                #pragma unroll
                for (int mt = 0; mt < 2; ++mt) {
                    acc[mt][0][g][nt] = __builtin_amdgcn_mfma_f32_16x16x32_bf16(a_a[mt], bi, acc[mt][0][g][nt], 0, 0, 0);
                    acc[mt][1][g][nt] = __builtin_amdgcn_mfma_f32_16x16x32_bf16(a_h[mt], bh, acc[mt][1][g][nt], 0, 0, 0);
                }
            }
        }
    }

    #pragma unroll
    for (int nt = 0; nt < 2; ++nt) {
        int col = w * 32 + nt * 16 + l15;
        float bir = bih[col], biz = bih[128 + col], bin = bih[256 + col];
        float bhr = bhh[col], bhz = bhh[128 + col], bhn = bhh[256 + col];
        float ga = gamma[col], be = beta[col], mu = mean[col];
        float iv = rsqrtf(var[col] + 1e-5f);
        #pragma unroll
        for (int mt = 0; mt < 2; ++mt) {
            #pragma unroll
            for (int r = 0; r < 4; ++r) {
                int nl = mt * 16 + q * 4 + r;
                int node = n0 + nl;
                if (node < NN) {
                    float ir = acc[mt][0][0][nt][r] + bir;
                    float iz = acc[mt][0][1][nt][r] + biz;
                    float in = acc[mt][0][2][nt][r] + bin;
                    float hr = acc[mt][1][0][nt][r] + bhr;
                    float hz = acc[mt][1][1][nt][r] + bhz;
                    float hn = acc[mt][1][2][nt][r] + bhn;
                    float rg = sigmoidf_(ir + hr);
                    float zg = sigmoidf_(iz + hz);
                    float ng = tanhf(in + rg * hn);
                    float hv = hf[nl][col];
                    float hnew = (1.f - zg) * ng + zg * hv;
                    float bn = (hnew - mu) * iv * ga + be;
                    float out = hv + bn;
                    h[(size_t)node * H + col] = out;
                    h_bf[(size_t)node * H + col] = f2bf(out);
                }
            }
        }
    }
}

// ---------------------------------------------------------------------------
// readout
__device__ __forceinline__ unsigned fkey(float f) {
    unsigned b = __float_as_uint(f);
    return (b & 0x80000000u) ? ~b : (b | 0x80000000u);
}
__device__ __forceinline__ float funkey(unsigned k) {
    unsigned b = (k & 0x80000000u) ? (k & 0x7FFFFFFFu) : ~k;
    return __uint_as_float(b);
}

__global__ __launch_bounds__(256) void k_ro_init(float* __restrict__ gsum,
                                                 unsigned* __restrict__ gmaxb,
                                                 float* __restrict__ gcnt) {
    int i = blockIdx.x * 256 + threadIdx.x;
    if (i < NG * H) { gsum[i] = 0.f; gmaxb[i] = 0u; }
    if (i < NG) gcnt[i] = 0.f;
}

// run-scan readout over sorted batch: one atomic per (run, col)
__global__ __launch_bounds__(256) void k_ro_scan(const float* __restrict__ h,
                                                 const int* __restrict__ batch,
                                                 float* __restrict__ gsum,
                                                 unsigned* __restrict__ gmaxb,
                                                 float* __restrict__ gcnt) {
    __shared__ int bt_s[64];
    const int t = threadIdx.x;
    const int n0 = blockIdx.x * 64;   // grid 782
    if (t < 64) bt_s[t] = (n0 + t < NN) ? batch[n0 + t] : -1;
    __syncthreads();

    int c = t & 127, hh = t >> 7;
    float sum = 0.f, mx = -3.4e38f, cnt = 0.f;
    int prev = bt_s[hh * 32];
    #pragma unroll 4
    for (int i = 0; i < 32; ++i) {
        int e = hh * 32 + i;
        int g = bt_s[e];
        if (g != prev) {
            if (prev >= 0) {
                atomicAdd(&gsum[prev * H + c], sum);
                atomicMax(&gmaxb[prev * H + c], fkey(mx));
                if (c == 0) atomicAdd(&gcnt[prev], cnt);
            }
            sum = 0.f; mx = -3.4e38f; cnt = 0.f;
            prev = g;
        }
        if (g >= 0) {
            float v = h[(size_t)(n0 + e) * H + c];
            sum += v;
            mx = fmaxf(mx, v);
            cnt += 1.f;
        }
    }
    if (prev >= 0) {
        atomicAdd(&gsum[prev * H + c], sum);
        atomicMax(&gmaxb[prev * H + c], fkey(mx));
        if (c == 0) atomicAdd(&gcnt[prev], cnt);
    }
}

__global__ __launch_bounds__(128) void k_ro_final(const float* __restrict__ gsum,
                                                  const unsigned* __restrict__ gmaxb,
                                                  const float* __restrict__ gcnt,
                                                  const float* __restrict__ row,
                                                  const float* __restrict__ rob,
                                                  float* __restrict__ out) {
    __shared__ float cat[256];
    const int g = blockIdx.x, t = threadIdx.x;
    float cnt = gcnt[g];
    float inv = 1.f / fmaxf(cnt, 1.f);
    cat[t] = gsum[g * H + t] * inv;
    float mx = funkey(gmaxb[g * H + t]);
    cat[128 + t] = (cnt > 0.f) ? mx : 0.f;
    __syncthreads();
    float acc = rob[t];
    #pragma unroll 4
    for (int k = 0; k < 256; ++k) acc += cat[k] * row[k * H + t];
    out[g * H + t] = fmaxf(acc, 0.f);
}

// ---------------------------------------------------------------------------
extern "C" void kernel_launch(void* const* d_in, const int* in_sizes, int n_in,
                              void* d_out, int out_size, void* d_ws, size_t ws_size,
                              hipStream_t stream) {
    const float* x        = (const float*)d_in[0];
    const int*   ei       = (const int*)d_in[1];
    const float* ea       = (const float*)d_in[2];
    const int*   batch    = (const int*)d_in[3];
    const float* lin_in_w = (const float*)d_in[5];
    const float* lin_in_b = (const float*)d_in[6];
    const float* msg_w1   = (const float*)d_in[7];
    const float* msg_b1   = (const float*)d_in[8];
    const float* msg_w2   = (const float*)d_in[9];
    const float* msg_b2   = (const float*)d_in[10];
    const float* bn_gamma = (const float*)d_in[11];
    const float* bn_beta  = (const float*)d_in[12];
    const float* bn_mean  = (const float*)d_in[13];
    const float* bn_var   = (const float*)d_in[14];
    const float* gru_wih  = (const float*)d_in[15];
    const float* gru_whh  = (const float*)d_in[16];
    const float* gru_bih  = (const float*)d_in[17];
    const float* gru_bhh  = (const float*)d_in[18];
    const float* ro_w     = (const float*)d_in[19];
    const float* ro_b     = (const float*)d_in[20];

    float* ws = (float*)d_ws;
    float*          h     = ws;                                 // 6.4M f
    float*          agg   = ws + 6400000;                       // 6.4M f
    unsigned short* h_bf  = (unsigned short*)(ws + 12800000);   // 3.2M f
    unsigned short* p_bf  = (unsigned short*)(ws + 16000000);   // 3.2M f
    float*          gsum  = ws + 19200000;                      // 32768
    unsigned*       gmaxb = (unsigned*)(ws + 19232768);         // 32768
    float*          gcnt  = ws + 19265536;                      // 256
    unsigned short* wgru  = (unsigned short*)(ws + 19265792);   // 147456 f
    unsigned short* w1et  = (unsigned short*)(ws + 19413248);   // 6144 f
    unsigned short* w2t   = (unsigned short*)(ws + 19419392);   // 24576 f
    unsigned short* w1ht  = (unsigned short*)(ws + 19443968);   // 24576 f
    unsigned short* winT  = (unsigned short*)(ws + 19468544);   // 8192 f
    int*            cnts  = (int*)(ws + 19476736);              // 50176
    int*            incl  = (int*)(ws + 19526912);              // 50176
    int*            cur   = (int*)(ws + 19577088);              // 50176
    int*            bsum  = (int*)(ws + 19627264);              // 256
    int*            perm  = (int*)(ws + 19627520);              // 800000
    // end: 20,427,520 floats (~81.7 MB)

    // weight prep (bf16, B-layout)
    k_prep<<<1648, 256, 0, stream>>>(gru_wih, gru_whh, msg_w1, msg_w2, lin_in_w,
                                     wgru, w1et, w2t, w1ht, winT);

    // counting sort of edges by dst -> perm
    k_sort_zero<<<196, 256, 0, stream>>>(cnts);
    k_hist<<<3125, 256, 0, stream>>>(ei, cnts);
    k_scan1<<<196, 256, 0, stream>>>(cnts, incl, bsum);
    k_scan2<<<1, 256, 0, stream>>>(bsum);
    k_scan3<<<196, 256, 0, stream>>>(cnts, incl, bsum, cur);
    k_scatter_perm<<<3125, 256, 0, stream>>>(ei, cur, perm);

    // input projection: h = relu(x @ Win + b)
    k_mfma_gemm<true, true, true, true><<<1563, 256, 0, stream>>>(
        x, nullptr, winT, lin_in_b, h, h_bf, NN);

    for (int l = 0; l < NL; ++l) {
        // p_bf = bf16(h_bf @ W1h^T)
        k_mfma_gemm<false, false, false, false><<<1563, 256, 0, stream>>>(
            nullptr, h_bf, w1ht + (size_t)l * 16384, nullptr, nullptr, p_bf, NN);
        // agg = 0
        k_zero4<<<6250, 256, 0, stream>>>((float4*)agg, 1600000);
        // edge MLP (MFMA) + sorted run-reduction
        k_edge_mfma<<<1024, 256, 0, stream>>>(p_bf, ea, ei, perm,
                                              w1et + (size_t)l * 4096, msg_b1 + l * 128,
                                              w2t + (size_t)l * 16384, msg_b2 + l * 128,
                                              agg);
        // GRU + BN + residual (MFMA)
        k_gru_mfma<<<1563, 256, 0, stream>>>(agg, h, h_bf,
                                             wgru + (size_t)l * 49152,
                                             wgru + (size_t)(NL + l) * 49152,
                                             gru_bih + l * 384, gru_bhh + l * 384,
                                             bn_gamma + l * 128, bn_beta + l * 128,
                                             bn_mean + l * 128, bn_var + l * 128);
    }

    // readout
    k_ro_init<<<128, 256, 0, stream>>>(gsum, gmaxb, gcnt);
    k_ro_scan<<<782, 256, 0, stream>>>(h, batch, gsum, gmaxb, gcnt);
    k_ro_final<<<NG, 128, 0, stream>>>(gsum, gmaxb, gcnt, ro_w, ro_b, (float*)d_out);
}